// Round 1
// baseline (115.159 us; speedup 1.0000x reference)
//
#include <hip/hip_runtime.h>
#include <stdint.h>

// FusedFP4Linear: out = gelu(x @ dequant(w_fp4)^T + bias)
// M=128, K=4096, N=16384. Weights: [N, K/2] int32, each holding one packed
// byte = two FP4 (E2M1) indices (hi = even k, lo = odd k).
// Strategy: bf16 MFMA GEMM. x pre-converted to bf16 (ws). Weights dequantized
// during LDS staging via 256-entry LUT (byte -> two packed bf16). Per-channel
// scale + bias + exact GELU fused in epilogue (scale applied post-accum, fp32).

#define M_DIM 128
#define K_DIM 4096
#define N_DIM 16384
#define KP    (K_DIM/2)     // ints per weight row = 2048
#define BN    64
#define BK    128           // k elements per LDS tile
#define BKI   (BK/2)        // ints per row per tile = 64
#define LDT   (BK + 8)      // padded ushort stride = 136 (2-way bank alias = free)
#define NT    512           // 8 waves

typedef __attribute__((ext_vector_type(8))) __bf16 bf16x8;
typedef __attribute__((ext_vector_type(4))) float  f32x4;
typedef unsigned short ushort_t;

__device__ __forceinline__ unsigned f2b_bits(float f) {
  unsigned u = __builtin_bit_cast(unsigned, f);
  u += 0x7FFFu + ((u >> 16) & 1u);   // RNE
  return u >> 16;
}

__global__ void convert_x_kernel(const float* __restrict__ x,
                                 ushort_t* __restrict__ xb) {
  int i = (blockIdx.x * blockDim.x + threadIdx.x) * 4;
  float4 v = *(const float4*)(x + i);
  ushort4 p;
  p.x = (ushort_t)f2b_bits(v.x);
  p.y = (ushort_t)f2b_bits(v.y);
  p.z = (ushort_t)f2b_bits(v.z);
  p.w = (ushort_t)f2b_bits(v.w);
  *(ushort4*)(xb + i) = p;
}

template<bool USE_XB>
__global__ __launch_bounds__(NT) void fp4gemm_kernel(
    const void* __restrict__ xsrc,        // bf16 xb (ws) or fp32 x
    const int*  __restrict__ wq,          // [N, KP] packed
    const float* __restrict__ scale,      // [N]
    const float* __restrict__ bias,       // [N]
    float* __restrict__ out) {            // [M, N]
  __shared__ ushort_t As[M_DIM][LDT];     // 34816 B
  __shared__ ushort_t Bs[BN][LDT];        // 17408 B
  __shared__ unsigned tab[256];           // byte -> (bf16(hi) | bf16(lo)<<16)

  const int t   = threadIdx.x;
  const int w   = t >> 6;        // wave 0..7
  const int l   = t & 63;
  const int l16 = l & 15;
  const int lq  = l >> 4;        // 0..3
  const int mh  = w >> 2;        // m-half (0..1): rows mh*64..+63
  const int nc  = w & 3;         // 16-col slice within BN

  if (t < 256) {
    const float FV[16] = {0.f, 0.5f, 1.f, 1.5f, 2.f, 3.f, 4.f, 6.f,
                          0.f, -0.5f, -1.f, -1.5f, -2.f, -3.f, -4.f, -6.f};
    unsigned hi = f2b_bits(FV[(t >> 4) & 15]);   // exact in bf16, RNE is no-op
    unsigned lo = f2b_bits(FV[t & 15]);
    tab[t] = hi | (lo << 16);
  }

  const int n0   = blockIdx.x * BN;
  const int brow = t >> 3;          // 0..63  (B staging row)
  const int bic  = (t & 7) * 8;     // int col 0..56 (8 ints per thread)

  f32x4 acc[4] = {f32x4{0,0,0,0}, f32x4{0,0,0,0}, f32x4{0,0,0,0}, f32x4{0,0,0,0}};

  for (int kt = 0; kt < K_DIM / BK; ++kt) {
    // ---- global loads (A: 4x16B worth of bf16, B: 8 packed ints) ----
    uint4 aL[4];
#pragma unroll
    for (int i = 0; i < 4; ++i) {
      int c = i * NT + t;
      int row = c >> 4, cc = c & 15;
      size_t off = (size_t)row * K_DIM + kt * BK + cc * 8;   // element offset
      if constexpr (USE_XB) {
        aL[i] = *(const uint4*)((const ushort_t*)xsrc + off);
      } else {
        const float* xf = (const float*)xsrc + off;
        float4 v0 = *(const float4*)(xf);
        float4 v1 = *(const float4*)(xf + 4);
        aL[i] = make_uint4(f2b_bits(v0.x) | (f2b_bits(v0.y) << 16),
                           f2b_bits(v0.z) | (f2b_bits(v0.w) << 16),
                           f2b_bits(v1.x) | (f2b_bits(v1.y) << 16),
                           f2b_bits(v1.z) | (f2b_bits(v1.w) << 16));
      }
    }
    const int* wrow = wq + (size_t)(n0 + brow) * KP + kt * BKI + bic;
    int4 b0 = *(const int4*)(wrow);
    int4 b1 = *(const int4*)(wrow + 4);

    __syncthreads();   // previous tile fully consumed (also covers tab init)

    // ---- LDS writes ----
#pragma unroll
    for (int i = 0; i < 4; ++i) {
      int c = i * NT + t;
      int row = c >> 4, cc = c & 15;
      *(uint4*)&As[row][cc * 8] = aL[i];
    }
    {
      unsigned u0 = tab[b0.x & 255], u1 = tab[b0.y & 255];
      unsigned u2 = tab[b0.z & 255], u3 = tab[b0.w & 255];
      unsigned u4 = tab[b1.x & 255], u5 = tab[b1.y & 255];
      unsigned u6 = tab[b1.z & 255], u7 = tab[b1.w & 255];
      *(uint4*)&Bs[brow][bic * 2]     = make_uint4(u0, u1, u2, u3);
      *(uint4*)&Bs[brow][bic * 2 + 8] = make_uint4(u4, u5, u6, u7);
    }
    __syncthreads();

    // ---- MFMA over this K-tile ----
#pragma unroll
    for (int ks = 0; ks < BK / 32; ++ks) {
      const int ko = ks * 32 + lq * 8;
      bf16x8 bf = *(const bf16x8*)&Bs[nc * 16 + l16][ko];
#pragma unroll
      for (int r = 0; r < 4; ++r) {
        bf16x8 af = *(const bf16x8*)&As[mh * 64 + r * 16 + l16][ko];
        acc[r] = __builtin_amdgcn_mfma_f32_16x16x32_bf16(af, bf, acc[r], 0, 0, 0);
      }
    }
  }

  // ---- epilogue: scale, bias, exact GELU, store ----
  const int ng = n0 + nc * 16 + l16;
  const float s  = scale[ng];
  const float bb = bias[ng];
#pragma unroll
  for (int r = 0; r < 4; ++r) {
#pragma unroll
    for (int j = 0; j < 4; ++j) {
      int m = mh * 64 + r * 16 + lq * 4 + j;
      float y = acc[r][j] * s + bb;
      float g = 0.5f * y * (1.0f + erff(y * 0.70710678118654752f));
      out[(size_t)m * N_DIM + ng] = g;
    }
  }
}

extern "C" void kernel_launch(void* const* d_in, const int* in_sizes, int n_in,
                              void* d_out, int out_size, void* d_ws, size_t ws_size,
                              hipStream_t stream) {
  const float* x     = (const float*)d_in[0];
  const int*   wq    = (const int*)d_in[1];
  const float* scale = (const float*)d_in[2];
  const float* bias  = (const float*)d_in[3];
  float* out = (float*)d_out;

  const size_t xb_bytes = (size_t)M_DIM * K_DIM * sizeof(ushort_t);  // 1 MB
  if (ws_size >= xb_bytes) {
    ushort_t* xb = (ushort_t*)d_ws;
    convert_x_kernel<<<(M_DIM * K_DIM) / (256 * 4), 256, 0, stream>>>(x, xb);
    fp4gemm_kernel<true><<<N_DIM / BN, NT, 0, stream>>>(xb, wq, scale, bias, out);
  } else {
    fp4gemm_kernel<false><<<N_DIM / BN, NT, 0, stream>>>(x, wq, scale, bias, out);
  }
}